// Round 2
// baseline (4112.407 us; speedup 1.0000x reference)
//
#include <hip/hip_runtime.h>
#include <hip/hip_bf16.h>

#define HID   1024
#define EMB   512
#define BATCH 128
#define TT    256
#define OUTN  4

typedef short bf16x8 __attribute__((ext_vector_type(8)));   // 8 bf16 in 4 VGPRs
typedef float f32x4  __attribute__((ext_vector_type(4)));

__device__ __forceinline__ float bf2f(unsigned short h) {
    return __uint_as_float(((unsigned)h) << 16);
}
__device__ __forceinline__ unsigned short f2bf(float f) {
    unsigned u = __float_as_uint(f);
    u += 0x7FFFu + ((u >> 16) & 1u);      // RNE
    return (unsigned short)(u >> 16);
}
__device__ __forceinline__ void cvt8(const float* s, unsigned short* d) {
    float4 a = *(const float4*)s, b = *(const float4*)(s + 4);
    unsigned short t[8] = {f2bf(a.x), f2bf(a.y), f2bf(a.z), f2bf(a.w),
                           f2bf(b.x), f2bf(b.y), f2bf(b.z), f2bf(b.w)};
    *(int4*)d = *(const int4*)t;
}

// ---------------------------------------------------------------------------
// Phase A: pre0[t*128+b][i] = emb[fx[b][t]] . Wx0[i] + bx0[i] + bh0[i]   (bf16 out)
// M = 32768 (row = t*128+b), N = 1024, K = 512. f32 inputs -> bf16 MFMA.
// ---------------------------------------------------------------------------
__global__ __launch_bounds__(256) void prefx_kernel(
    const int* __restrict__ fx, const float* __restrict__ emb,
    const float* __restrict__ wx0, const float* __restrict__ bx0,
    const float* __restrict__ bh0, unsigned short* __restrict__ pre0)
{
    __shared__ __align__(16) unsigned short A[64 * 520];   // bf16-staged emb rows
    const int mtile = blockIdx.x >> 2;        // 0..511
    const int ntile = blockIdx.x & 3;         // 0..3  (256 cols each)
    const int tid = threadIdx.x;

    {   // stage 64 gathered emb rows (f32 -> bf16); 4 threads per row, 128 elems each
        const int row = tid >> 2, part = tid & 3;
        const int r = mtile * 64 + row;               // global pre0 row = t*128+b
        const int t = r >> 7, b = r & 127;
        const int v = fx[b * TT + t];
        const float* src = emb + (size_t)v * EMB + part * 128;
        unsigned short* dst = A + row * 520 + part * 128;
        #pragma unroll
        for (int i = 0; i < 128; i += 8) cvt8(src + i, dst + i);
    }
    __syncthreads();

    const int wave = tid >> 6, lane = tid & 63, q = lane >> 4, nl = lane & 15;
    const int col0 = ntile * 256 + wave * 64;

    f32x4 acc[4][4] = {};                      // [mt][nt]
    for (int kc = 0; kc < 16; ++kc) {
        bf16x8 bfr[4], afr[4];
        #pragma unroll
        for (int nt = 0; nt < 4; ++nt) {
            const float* wp = wx0 + (size_t)(col0 + nt * 16 + nl) * EMB + kc * 32 + q * 8;
            float4 wa = *(const float4*)wp, wb = *(const float4*)(wp + 4);
            bf16x8 f;
            f[0] = (short)f2bf(wa.x); f[1] = (short)f2bf(wa.y);
            f[2] = (short)f2bf(wa.z); f[3] = (short)f2bf(wa.w);
            f[4] = (short)f2bf(wb.x); f[5] = (short)f2bf(wb.y);
            f[6] = (short)f2bf(wb.z); f[7] = (short)f2bf(wb.w);
            bfr[nt] = f;
        }
        #pragma unroll
        for (int mt = 0; mt < 4; ++mt)
            afr[mt] = *(const bf16x8*)(A + (mt * 16 + nl) * 520 + kc * 32 + q * 8);
        #pragma unroll
        for (int mt = 0; mt < 4; ++mt)
            #pragma unroll
            for (int nt = 0; nt < 4; ++nt)
                acc[mt][nt] = __builtin_amdgcn_mfma_f32_16x16x32_bf16(afr[mt], bfr[nt], acc[mt][nt], 0, 0, 0);
    }

    #pragma unroll
    for (int nt = 0; nt < 4; ++nt) {
        const int gc = col0 + nt * 16 + nl;            // C col = lane&15
        const float bias = bx0[gc] + bh0[gc];
        #pragma unroll
        for (int mt = 0; mt < 4; ++mt)
            #pragma unroll
            for (int r = 0; r < 4; ++r) {              // C row = q*4+r
                const int grow = mtile * 64 + mt * 16 + q * 4 + r;
                pre0[(size_t)grow * HID + gc] = f2bf(acc[mt][nt][r] + bias);
            }
    }
}

// ---------------------------------------------------------------------------
// Cluster barrier: monotonic counter; release fence (buffer_wbl2) publishes h,
// acquire fence (buffer_inv) invalidates stale L1/L2. One cache-op each side.
// ---------------------------------------------------------------------------
__device__ __forceinline__ void cluster_barrier(unsigned* bar, unsigned* count, int nwg) {
    __syncthreads();                          // all block threads' stores issued (vmcnt drained)
    if (threadIdx.x == 0) {
        __builtin_amdgcn_fence(__ATOMIC_RELEASE, "agent");
        *count += 1;
        const unsigned target = (*count) * (unsigned)nwg;
        __hip_atomic_fetch_add(bar, 1u, __ATOMIC_RELAXED, __HIP_MEMORY_SCOPE_AGENT);
        while (__hip_atomic_load(bar, __ATOMIC_RELAXED, __HIP_MEMORY_SCOPE_AGENT) < target)
            __builtin_amdgcn_s_sleep(1);
        __builtin_amdgcn_fence(__ATOMIC_ACQUIRE, "agent");
    }
    __syncthreads();
}

// ---------------------------------------------------------------------------
// Phase B: persistent recurrence. 256 WGs x 512 thr, 1 WG/CU (115 KB LDS).
// 4 clusters x 64 WGs; cluster c owns batch rows [32c,32c+32); WG owns 16 HID rows.
// One barrier/step (between G1 and G2) is sufficient: it also separates
// G2(t-1)/G2(t) and G1(t)/G1(t+1); h0/h1 are parity double-buffered.
// ---------------------------------------------------------------------------
__global__ __launch_bounds__(512) void rnn_step_kernel(
    const unsigned short* __restrict__ pre0,  // bf16 (ours)
    const float* __restrict__ whh0,
    const float* __restrict__ wx1,
    const float* __restrict__ whh1,
    const float* __restrict__ bx1,
    const float* __restrict__ bh1,
    const float* __restrict__ fcw,
    const float* __restrict__ fcb,
    unsigned short* __restrict__ h0buf,     // [2][128][1024] bf16 (zeroed)
    unsigned short* __restrict__ h1buf,     // [2][128][1024] bf16 (zeroed)
    unsigned* __restrict__ bars,            // 4 clusters x 32 uints (zeroed)
    float* __restrict__ out)                // [128][4] f32
{
    __shared__ __align__(16) unsigned short W1[16 * 1032];   // Whh0 rows r0..r0+15 (bf16)
    __shared__ __align__(16) unsigned short W2[16 * 2056];   // [Wx1|Whh1] rows (bf16)
    __shared__ float partials[8][2][256];                    // [wave][mtile][row*16+col]
    __shared__ float bias1s[16];

    const int bid = blockIdx.x;
    const int cluster = bid & 3;
    const int wg = bid >> 2;                 // 0..63
    const int r0 = wg * 16;
    const int tid = threadIdx.x;
    const int wave = tid >> 6, lane = tid & 63, q = lane >> 4, nl = lane & 15;

    {   // preload weights into LDS (f32 -> bf16)
        const int row = tid >> 5, seg = tid & 31;
        {   // W1: 32 elems per thread
            const float* src = whh0 + (size_t)(r0 + row) * HID + seg * 32;
            unsigned short* dst = W1 + row * 1032 + seg * 32;
            #pragma unroll
            for (int i = 0; i < 32; i += 8) cvt8(src + i, dst + i);
        }
        {   // W2: 64 elems per thread; k<1024 from Wx1, else Whh1
            const int k2 = seg * 64;
            const float* s2 = (k2 < HID)
                ? (wx1  + (size_t)(r0 + row) * HID + k2)
                : (whh1 + (size_t)(r0 + row) * HID + (k2 - HID));
            unsigned short* d2 = W2 + row * 2056 + k2;
            #pragma unroll
            for (int i = 0; i < 64; i += 8) cvt8(s2 + i, d2 + i);
        }
    }
    if (tid < 16) bias1s[tid] = bx1[r0 + tid] + bh1[r0 + tid];
    __syncthreads();

    const int b_l = tid >> 4;                // 0..31: local batch row (reduce phase)
    const int nn = tid & 15;                 // local HID col
    const int mt_r = b_l >> 4, row_r = b_l & 15;
    unsigned barcount = 0;
    unsigned* bar = bars + cluster * 32;     // 128B-separated counters

    #pragma unroll 1
    for (int t = 0; t < TT; ++t) {
        const int pin = t & 1;
        const unsigned short* h0r = h0buf + (size_t)pin * (BATCH * HID);
        unsigned short*       h0w = h0buf + (size_t)(pin ^ 1) * (BATCH * HID);
        const unsigned short* h1r = h1buf + (size_t)pin * (BATCH * HID);
        unsigned short*       h1w = h1buf + (size_t)(pin ^ 1) * (BATCH * HID);

        // prefetch this thread's pre0 element (used after G1's MFMA)
        const float pre_v = bf2f(pre0[(size_t)(t * BATCH + cluster * 32 + b_l) * HID + r0 + nn]);

        // ---- G1: h0_new = tanh(pre0 + h0 @ Whh0^T), K=1024 split across 8 waves ----
        f32x4 c0 = {0.f, 0.f, 0.f, 0.f}, c1 = {0.f, 0.f, 0.f, 0.f};
        #pragma unroll
        for (int j = 0; j < 4; ++j) {
            const int k0 = (wave * 4 + j) * 32 + q * 8;
            bf16x8 bfr = *(const bf16x8*)(W1 + nl * 1032 + k0);
            bf16x8 a0  = *(const bf16x8*)(h0r + (size_t)(cluster * 32 + nl) * HID + k0);
            bf16x8 a1  = *(const bf16x8*)(h0r + (size_t)(cluster * 32 + 16 + nl) * HID + k0);
            c0 = __builtin_amdgcn_mfma_f32_16x16x32_bf16(a0, bfr, c0, 0, 0, 0);
            c1 = __builtin_amdgcn_mfma_f32_16x16x32_bf16(a1, bfr, c1, 0, 0, 0);
        }
        #pragma unroll
        for (int r = 0; r < 4; ++r) {
            partials[wave][0][(q * 4 + r) * 16 + nl] = c0[r];
            partials[wave][1][(q * 4 + r) * 16 + nl] = c1[r];
        }
        __syncthreads();
        {
            float s = pre_v;
            #pragma unroll
            for (int w = 0; w < 8; ++w) s += partials[w][mt_r][row_r * 16 + nn];
            h0w[(size_t)(cluster * 32 + b_l) * HID + r0 + nn] = f2bf(tanhf(s));
        }
        cluster_barrier(bar, &barcount, 64);

        // ---- G2: h1_new = tanh(bias1 + [h0_new|h1] @ [Wx1|Whh1]^T), K=2048 ----
        f32x4 d0 = {0.f, 0.f, 0.f, 0.f}, d1 = {0.f, 0.f, 0.f, 0.f};
        #pragma unroll
        for (int j = 0; j < 8; ++j) {
            const int kg = (wave * 8 + j) * 32 + q * 8;   // 32-chunk entirely on one side
            bf16x8 bfr = *(const bf16x8*)(W2 + nl * 2056 + kg);
            const unsigned short* ab = (kg < HID)
                ? (h0w + (size_t)(cluster * 32 + nl) * HID + kg)
                : (h1r + (size_t)(cluster * 32 + nl) * HID + (kg - HID));
            bf16x8 a0 = *(const bf16x8*)ab;
            bf16x8 a1 = *(const bf16x8*)(ab + (size_t)16 * HID);
            d0 = __builtin_amdgcn_mfma_f32_16x16x32_bf16(a0, bfr, d0, 0, 0, 0);
            d1 = __builtin_amdgcn_mfma_f32_16x16x32_bf16(a1, bfr, d1, 0, 0, 0);
        }
        #pragma unroll
        for (int r = 0; r < 4; ++r) {
            partials[wave][0][(q * 4 + r) * 16 + nl] = d0[r];
            partials[wave][1][(q * 4 + r) * 16 + nl] = d1[r];
        }
        __syncthreads();
        {
            float s = bias1s[nn];
            #pragma unroll
            for (int w = 0; w < 8; ++w) s += partials[w][mt_r][row_r * 16 + nn];
            h1w[(size_t)(cluster * 32 + b_l) * HID + r0 + nn] = f2bf(tanhf(s));
        }
        __syncthreads();   // protect partials before next iteration's G1 writes
    }

    // ---- FC head: out = h1 @ fcw^T + fcb (final h1 parity 0), f32 out ----
    cluster_barrier(bar, &barcount, 64);
    if (wg == 0 && tid < 128) {
        const int b = tid >> 2, o = tid & 3;
        const unsigned short* hrow = h1buf + (size_t)(cluster * 32 + b) * HID;  // parity 0
        const float* wrow = fcw + (size_t)o * HID;
        float s = fcb[o];
        for (int k = 0; k < HID; k += 8) {
            int4 hv = *(const int4*)(hrow + k);
            float4 w0 = *(const float4*)(wrow + k), w1 = *(const float4*)(wrow + k + 4);
            const unsigned short* hu = (const unsigned short*)&hv;
            s += bf2f(hu[0]) * w0.x + bf2f(hu[1]) * w0.y + bf2f(hu[2]) * w0.z + bf2f(hu[3]) * w0.w
               + bf2f(hu[4]) * w1.x + bf2f(hu[5]) * w1.y + bf2f(hu[6]) * w1.z + bf2f(hu[7]) * w1.w;
        }
        out[(cluster * 32 + b) * OUTN + o] = s;
    }
}

// ---------------------------------------------------------------------------
extern "C" void kernel_launch(void* const* d_in, const int* in_sizes, int n_in,
                              void* d_out, int out_size, void* d_ws, size_t ws_size,
                              hipStream_t stream) {
    const int*   fx   = (const int*)d_in[0];
    const float* emb  = (const float*)d_in[1];
    const float* wx0  = (const float*)d_in[2];
    const float* bx0  = (const float*)d_in[3];
    const float* whh0 = (const float*)d_in[4];
    const float* bh0  = (const float*)d_in[5];
    const float* wx1  = (const float*)d_in[6];
    const float* bx1  = (const float*)d_in[7];
    const float* whh1 = (const float*)d_in[8];
    const float* bh1  = (const float*)d_in[9];
    const float* fcw  = (const float*)d_in[10];
    const float* fcb  = (const float*)d_in[11];
    float* outp = (float*)d_out;

    char* ws = (char*)d_ws;
    unsigned*       bars  = (unsigned*)ws;                              // 4 KB
    unsigned short* h0buf = (unsigned short*)(ws + 4096);               // 512 KB
    unsigned short* h1buf = (unsigned short*)(ws + 4096 + 524288);      // 512 KB
    unsigned short* pre0  = (unsigned short*)(ws + 4096 + 2 * 524288);  // 64 MB bf16

    // zero barriers + h state (ws is poisoned 0xAA before every call)
    hipMemsetAsync(d_ws, 0, 4096 + 2 * 524288, stream);

    prefx_kernel<<<dim3(2048), dim3(256), 0, stream>>>(fx, emb, wx0, bx0, bh0, pre0);

    void* kargs[] = {(void*)&pre0, (void*)&whh0, (void*)&wx1, (void*)&whh1,
                     (void*)&bx1, (void*)&bh1, (void*)&fcw, (void*)&fcb,
                     (void*)&h0buf, (void*)&h1buf, (void*)&bars, (void*)&outp};
    hipLaunchCooperativeKernel((void*)rnn_step_kernel, dim3(256), dim3(512),
                               kargs, 0, stream);
}

// Round 3
// 2381.525 us; speedup vs baseline: 1.7268x; 1.7268x over previous
//
#include <hip/hip_runtime.h>
#include <hip/hip_bf16.h>

#define HID   1024
#define EMB   512
#define BATCH 128
#define TT    256
#define OUTN  4
#define BH    (BATCH * HID)

typedef short bf16x8 __attribute__((ext_vector_type(8)));   // 8 bf16 in 4 VGPRs
typedef float f32x4  __attribute__((ext_vector_type(4)));
typedef int   i32x4  __attribute__((ext_vector_type(4)));

__device__ __forceinline__ float bf2f(unsigned short h) {
    return __uint_as_float(((unsigned)h) << 16);
}
__device__ __forceinline__ unsigned short f2bf(float f) {
    unsigned u = __float_as_uint(f);
    u += 0x7FFFu + ((u >> 16) & 1u);      // RNE
    return (unsigned short)(u >> 16);
}
__device__ __forceinline__ void cvt8(const float* s, unsigned short* d) {
    float4 a = *(const float4*)s, b = *(const float4*)(s + 4);
    unsigned short t[8] = {f2bf(a.x), f2bf(a.y), f2bf(a.z), f2bf(a.w),
                           f2bf(b.x), f2bf(b.y), f2bf(b.z), f2bf(b.w)};
    *(int4*)d = *(const int4*)t;
}
__device__ __forceinline__ bf16x8 pack8(const float* s) {
    float4 a = *(const float4*)s, b = *(const float4*)(s + 4);
    bf16x8 f;
    f[0] = (short)f2bf(a.x); f[1] = (short)f2bf(a.y);
    f[2] = (short)f2bf(a.z); f[3] = (short)f2bf(a.w);
    f[4] = (short)f2bf(b.x); f[5] = (short)f2bf(b.y);
    f[6] = (short)f2bf(b.z); f[7] = (short)f2bf(b.w);
    return f;
}

// ---------------------------------------------------------------------------
// Phase A: pre0[t*128+b][i] = emb[fx[b][t]] . Wx0[i] + bx0[i] + bh0[i]   (bf16 out)
// (unchanged from round 1 — it passed)
// ---------------------------------------------------------------------------
__global__ __launch_bounds__(256) void prefx_kernel(
    const int* __restrict__ fx, const float* __restrict__ emb,
    const float* __restrict__ wx0, const float* __restrict__ bx0,
    const float* __restrict__ bh0, unsigned short* __restrict__ pre0)
{
    __shared__ __align__(16) unsigned short A[64 * 520];
    const int mtile = blockIdx.x >> 2;
    const int ntile = blockIdx.x & 3;
    const int tid = threadIdx.x;

    {
        const int row = tid >> 2, part = tid & 3;
        const int r = mtile * 64 + row;
        const int t = r >> 7, b = r & 127;
        const int v = fx[b * TT + t];
        const float* src = emb + (size_t)v * EMB + part * 128;
        unsigned short* dst = A + row * 520 + part * 128;
        #pragma unroll
        for (int i = 0; i < 128; i += 8) cvt8(src + i, dst + i);
    }
    __syncthreads();

    const int wave = tid >> 6, lane = tid & 63, q = lane >> 4, nl = lane & 15;
    const int col0 = ntile * 256 + wave * 64;

    f32x4 acc[4][4] = {};
    for (int kc = 0; kc < 16; ++kc) {
        bf16x8 bfr[4], afr[4];
        #pragma unroll
        for (int nt = 0; nt < 4; ++nt)
            bfr[nt] = pack8(wx0 + (size_t)(col0 + nt * 16 + nl) * EMB + kc * 32 + q * 8);
        #pragma unroll
        for (int mt = 0; mt < 4; ++mt)
            afr[mt] = *(const bf16x8*)(A + (mt * 16 + nl) * 520 + kc * 32 + q * 8);
        #pragma unroll
        for (int mt = 0; mt < 4; ++mt)
            #pragma unroll
            for (int nt = 0; nt < 4; ++nt)
                acc[mt][nt] = __builtin_amdgcn_mfma_f32_16x16x32_bf16(afr[mt], bfr[nt], acc[mt][nt], 0, 0, 0);
    }

    #pragma unroll
    for (int nt = 0; nt < 4; ++nt) {
        const int gc = col0 + nt * 16 + nl;
        const float bias = bx0[gc] + bh0[gc];
        #pragma unroll
        for (int mt = 0; mt < 4; ++mt)
            #pragma unroll
            for (int r = 0; r < 4; ++r) {
                const int grow = mtile * 64 + mt * 16 + q * 4 + r;
                pre0[(size_t)grow * HID + gc] = f2bf(acc[mt][nt][r] + bias);
            }
    }
}

// ---------------------------------------------------------------------------
// MALL-coherent bypass helpers (sc0 sc1 = bypass L1+L2, coherent at L3).
// Every asm block that issues vmem ends with s_waitcnt vmcnt(0), so the
// compiler's own waitcnt bookkeeping stays conservative-correct.
// ---------------------------------------------------------------------------
__device__ __forceinline__ void bypass_store16B(unsigned short* dst, i32x4 v) {
    asm volatile("global_store_dwordx4 %0, %1, off sc0 sc1\n\t"
                 "s_waitcnt vmcnt(0)"
                 :: "v"(dst), "v"(v) : "memory");
}

__device__ __forceinline__ void bypass_ld8_seq(const unsigned short* p, bf16x8 r[8]) {
    asm volatile(
        "global_load_dwordx4 %0, %8, off sc0 sc1\n\t"
        "global_load_dwordx4 %1, %8, off offset:16 sc0 sc1\n\t"
        "global_load_dwordx4 %2, %8, off offset:32 sc0 sc1\n\t"
        "global_load_dwordx4 %3, %8, off offset:48 sc0 sc1\n\t"
        "global_load_dwordx4 %4, %8, off offset:64 sc0 sc1\n\t"
        "global_load_dwordx4 %5, %8, off offset:80 sc0 sc1\n\t"
        "global_load_dwordx4 %6, %8, off offset:96 sc0 sc1\n\t"
        "global_load_dwordx4 %7, %8, off offset:112 sc0 sc1\n\t"
        "s_waitcnt vmcnt(0)"
        : "=&v"(r[0]), "=&v"(r[1]), "=&v"(r[2]), "=&v"(r[3]),
          "=&v"(r[4]), "=&v"(r[5]), "=&v"(r[6]), "=&v"(r[7])
        : "v"(p) : "memory");
}

// ---------------------------------------------------------------------------
// Cluster barrier: relaxed agent-scope atomics only. No cache maintenance —
// all cross-WG data moves via sc0sc1 bypass ops, already drained (vmcnt(0))
// inside their asm blocks before any thread reaches this barrier.
// ---------------------------------------------------------------------------
__device__ __forceinline__ void cluster_barrier(unsigned* bar, unsigned target) {
    __syncthreads();
    if (threadIdx.x == 0) {
        __hip_atomic_fetch_add(bar, 1u, __ATOMIC_RELAXED, __HIP_MEMORY_SCOPE_AGENT);
        while (__hip_atomic_load(bar, __ATOMIC_RELAXED, __HIP_MEMORY_SCOPE_AGENT) < target)
            __builtin_amdgcn_s_sleep(2);
    }
    __syncthreads();
}

// ---------------------------------------------------------------------------
// Phase B: persistent recurrence, fused supersteps.
// 256 WGs x 512 thr. 4 clusters x 64 WGs; cluster c owns batch [32c,32c+32);
// WG owns 16 HID cols. Weights live in REGISTERS (step-invariant fragments).
// Superstep t: [loads: G2(t) + G1(t+1)] -> MFMA -> reduce -> bypass-store
// h1(t), h0(t+1) -> barrier. One barrier + one MALL round-trip per step.
// ---------------------------------------------------------------------------
__global__ __launch_bounds__(512) void rnn_step_kernel(
    const unsigned short* __restrict__ pre0,  // bf16 (ours)
    const float* __restrict__ whh0,
    const float* __restrict__ wx1,
    const float* __restrict__ whh1,
    const float* __restrict__ bx1,
    const float* __restrict__ bh1,
    const float* __restrict__ fcw,
    const float* __restrict__ fcb,
    unsigned short* __restrict__ h0buf,     // [2][128][1024] bf16 (zeroed)
    unsigned short* __restrict__ h1buf,     // [2][128][1024] bf16 (zeroed)
    unsigned* __restrict__ bars,            // 4 clusters x 32 uints (zeroed)
    float* __restrict__ out)                // [128][4] f32
{
    __shared__ float partials[8][4][256];                 // [wave][tile][row*16+col] 32 KB
    __shared__ __align__(16) unsigned short hst[2][512];  // staged h tiles (bf16)

    const int bid = blockIdx.x;
    const int cluster = bid & 3;
    const int wg = bid >> 2;                 // 0..63
    const int r0 = wg * 16;
    const int tid = threadIdx.x;
    const int wave = tid >> 6, lane = tid & 63, q = lane >> 4, nl = lane & 15;

    // ---- step-invariant weight fragments in registers (48 VGPRs/lane) ----
    bf16x8 bw1[4], bw2[8];
    #pragma unroll
    for (int j = 0; j < 4; ++j) {
        const int k0 = (wave * 4 + j) * 32 + q * 8;
        bw1[j] = pack8(whh0 + (size_t)(r0 + nl) * HID + k0);
    }
    #pragma unroll
    for (int j = 0; j < 8; ++j) {
        const int kg = (wave * 8 + j) * 32 + q * 8;
        const float* src = (kg < HID) ? (wx1  + (size_t)(r0 + nl) * HID + kg)
                                      : (whh1 + (size_t)(r0 + nl) * HID + (kg - HID));
        bw2[j] = pack8(src);
    }

    const int b_l = tid >> 4;                // 0..31: local batch row (reduce phase)
    const int nn = tid & 15;                 // local HID col
    const int mt_r = b_l >> 4, row_r = b_l & 15;
    const float bias1_reg = bx1[r0 + nn] + bh1[r0 + nn];

    const size_t rowbase = (size_t)(cluster * 32 + nl) * HID + q * 8;
    unsigned barcount = 0;
    unsigned* bar = bars + cluster * 32;

    // ---- prologue: h0(0) = tanh(pre0(0)) (h0 init = 0), store parity 1 ----
    {
        const float pv = bf2f(pre0[(size_t)(cluster * 32 + b_l) * HID + r0 + nn]);
        hst[0][b_l * 16 + nn] = f2bf(tanhf(pv));
        __syncthreads();
        if (wave == 1) {
            const int row = lane >> 1, seg = (lane & 1) * 8;
            i32x4 v = *(const i32x4*)&hst[0][row * 16 + seg];
            unsigned short* dst = h0buf + (size_t)BH + (size_t)(cluster * 32 + row) * HID + r0 + seg;
            bypass_store16B(dst, v);
        }
        cluster_barrier(bar, ++barcount * 64u);
    }

    // ---- main loop: superstep t = [G2(t) || G1(t+1)] ----
    #pragma unroll 1
    for (int t = 0; t < TT - 1; ++t) {
        const int pin = t & 1;
        const unsigned short* h0_cur = h0buf + (size_t)(pin ^ 1) * BH;  // G1(t) output
        unsigned short*       h0_nxt = h0buf + (size_t)pin * BH;        // G1(t+1) dest
        const unsigned short* h1_prv = h1buf + (size_t)pin * BH;        // G2(t-1) output
        unsigned short*       h1_new = h1buf + (size_t)(pin ^ 1) * BH;  // G2(t) dest

        // cached prefetch of pre0 for t+1 (pre0 written by a previous dispatch)
        const float pre_v = bf2f(pre0[(size_t)((t + 1) * BATCH + cluster * 32 + b_l) * HID + r0 + nn]);

        // ---- combined bypass load phase: G2 (16) + G1-next (8) ----
        const unsigned short* pa2 = (wave < 4 ? h0_cur : h1_prv) + rowbase + (wave & 3) * 256;
        const unsigned short* pb2 = pa2 + (size_t)16 * HID;
        const unsigned short* pa1 = h0_cur + rowbase + wave * 128;
        const unsigned short* pb1 = pa1 + (size_t)16 * HID;

        bf16x8 A0, A1, A2, A3, A4, A5, A6, A7;    // G2 rows nl
        bf16x8 C0, C1, C2, C3, C4, C5, C6, C7;    // G2 rows nl+16
        bf16x8 E0, E1, E2, E3, F0, F1, F2, F3;    // G1-next rows nl / nl+16
        asm volatile(
            "global_load_dwordx4 %0, %24, off sc0 sc1\n\t"
            "global_load_dwordx4 %1, %24, off offset:64 sc0 sc1\n\t"
            "global_load_dwordx4 %2, %24, off offset:128 sc0 sc1\n\t"
            "global_load_dwordx4 %3, %24, off offset:192 sc0 sc1\n\t"
            "global_load_dwordx4 %4, %24, off offset:256 sc0 sc1\n\t"
            "global_load_dwordx4 %5, %24, off offset:320 sc0 sc1\n\t"
            "global_load_dwordx4 %6, %24, off offset:384 sc0 sc1\n\t"
            "global_load_dwordx4 %7, %24, off offset:448 sc0 sc1\n\t"
            "global_load_dwordx4 %8, %25, off sc0 sc1\n\t"
            "global_load_dwordx4 %9, %25, off offset:64 sc0 sc1\n\t"
            "global_load_dwordx4 %10, %25, off offset:128 sc0 sc1\n\t"
            "global_load_dwordx4 %11, %25, off offset:192 sc0 sc1\n\t"
            "global_load_dwordx4 %12, %25, off offset:256 sc0 sc1\n\t"
            "global_load_dwordx4 %13, %25, off offset:320 sc0 sc1\n\t"
            "global_load_dwordx4 %14, %25, off offset:384 sc0 sc1\n\t"
            "global_load_dwordx4 %15, %25, off offset:448 sc0 sc1\n\t"
            "global_load_dwordx4 %16, %26, off sc0 sc1\n\t"
            "global_load_dwordx4 %17, %26, off offset:64 sc0 sc1\n\t"
            "global_load_dwordx4 %18, %26, off offset:128 sc0 sc1\n\t"
            "global_load_dwordx4 %19, %26, off offset:192 sc0 sc1\n\t"
            "global_load_dwordx4 %20, %27, off sc0 sc1\n\t"
            "global_load_dwordx4 %21, %27, off offset:64 sc0 sc1\n\t"
            "global_load_dwordx4 %22, %27, off offset:128 sc0 sc1\n\t"
            "global_load_dwordx4 %23, %27, off offset:192 sc0 sc1\n\t"
            "s_waitcnt vmcnt(0)"
            : "=&v"(A0), "=&v"(A1), "=&v"(A2), "=&v"(A3),
              "=&v"(A4), "=&v"(A5), "=&v"(A6), "=&v"(A7),
              "=&v"(C0), "=&v"(C1), "=&v"(C2), "=&v"(C3),
              "=&v"(C4), "=&v"(C5), "=&v"(C6), "=&v"(C7),
              "=&v"(E0), "=&v"(E1), "=&v"(E2), "=&v"(E3),
              "=&v"(F0), "=&v"(F1), "=&v"(F2), "=&v"(F3)
            : "v"(pa2), "v"(pb2), "v"(pa1), "v"(pb1)
            : "memory");

        // ---- MFMA phase ----
        f32x4 d0 = {0.f,0.f,0.f,0.f}, d1 = {0.f,0.f,0.f,0.f};   // G2
        f32x4 c0 = {0.f,0.f,0.f,0.f}, c1 = {0.f,0.f,0.f,0.f};   // G1-next
        d0 = __builtin_amdgcn_mfma_f32_16x16x32_bf16(A0, bw2[0], d0, 0,0,0);
        d1 = __builtin_amdgcn_mfma_f32_16x16x32_bf16(C0, bw2[0], d1, 0,0,0);
        d0 = __builtin_amdgcn_mfma_f32_16x16x32_bf16(A1, bw2[1], d0, 0,0,0);
        d1 = __builtin_amdgcn_mfma_f32_16x16x32_bf16(C1, bw2[1], d1, 0,0,0);
        d0 = __builtin_amdgcn_mfma_f32_16x16x32_bf16(A2, bw2[2], d0, 0,0,0);
        d1 = __builtin_amdgcn_mfma_f32_16x16x32_bf16(C2, bw2[2], d1, 0,0,0);
        d0 = __builtin_amdgcn_mfma_f32_16x16x32_bf16(A3, bw2[3], d0, 0,0,0);
        d1 = __builtin_amdgcn_mfma_f32_16x16x32_bf16(C3, bw2[3], d1, 0,0,0);
        d0 = __builtin_amdgcn_mfma_f32_16x16x32_bf16(A4, bw2[4], d0, 0,0,0);
        d1 = __builtin_amdgcn_mfma_f32_16x16x32_bf16(C4, bw2[4], d1, 0,0,0);
        d0 = __builtin_amdgcn_mfma_f32_16x16x32_bf16(A5, bw2[5], d0, 0,0,0);
        d1 = __builtin_amdgcn_mfma_f32_16x16x32_bf16(C5, bw2[5], d1, 0,0,0);
        d0 = __builtin_amdgcn_mfma_f32_16x16x32_bf16(A6, bw2[6], d0, 0,0,0);
        d1 = __builtin_amdgcn_mfma_f32_16x16x32_bf16(C6, bw2[6], d1, 0,0,0);
        d0 = __builtin_amdgcn_mfma_f32_16x16x32_bf16(A7, bw2[7], d0, 0,0,0);
        d1 = __builtin_amdgcn_mfma_f32_16x16x32_bf16(C7, bw2[7], d1, 0,0,0);
        c0 = __builtin_amdgcn_mfma_f32_16x16x32_bf16(E0, bw1[0], c0, 0,0,0);
        c1 = __builtin_amdgcn_mfma_f32_16x16x32_bf16(F0, bw1[0], c1, 0,0,0);
        c0 = __builtin_amdgcn_mfma_f32_16x16x32_bf16(E1, bw1[1], c0, 0,0,0);
        c1 = __builtin_amdgcn_mfma_f32_16x16x32_bf16(F1, bw1[1], c1, 0,0,0);
        c0 = __builtin_amdgcn_mfma_f32_16x16x32_bf16(E2, bw1[2], c0, 0,0,0);
        c1 = __builtin_amdgcn_mfma_f32_16x16x32_bf16(F2, bw1[2], c1, 0,0,0);
        c0 = __builtin_amdgcn_mfma_f32_16x16x32_bf16(E3, bw1[3], c0, 0,0,0);
        c1 = __builtin_amdgcn_mfma_f32_16x16x32_bf16(F3, bw1[3], c1, 0,0,0);

        // ---- reduce across 8 waves via LDS ----
        #pragma unroll
        for (int r = 0; r < 4; ++r) {
            const int idx = (q * 4 + r) * 16 + nl;
            partials[wave][0][idx] = d0[r];
            partials[wave][1][idx] = d1[r];
            partials[wave][2][idx] = c0[r];
            partials[wave][3][idx] = c1[r];
        }
        __syncthreads();
        {
            const int idx = row_r * 16 + nn;
            float s1 = bias1_reg, s0 = pre_v;
            #pragma unroll
            for (int w = 0; w < 8; ++w) {
                s1 += partials[w][mt_r][idx];
                s0 += partials[w][2 + mt_r][idx];
            }
            hst[1][b_l * 16 + nn] = f2bf(tanhf(s1));   // h1(t)
            hst[0][b_l * 16 + nn] = f2bf(tanhf(s0));   // h0(t+1)
        }
        __syncthreads();

        // ---- bypass stores: wave0 -> h1(t), wave1 -> h0(t+1) ----
        if (wave == 0) {
            const int row = lane >> 1, seg = (lane & 1) * 8;
            i32x4 v = *(const i32x4*)&hst[1][row * 16 + seg];
            bypass_store16B(h1_new + (size_t)(cluster * 32 + row) * HID + r0 + seg, v);
        } else if (wave == 1) {
            const int row = lane >> 1, seg = (lane & 1) * 8;
            i32x4 v = *(const i32x4*)&hst[0][row * 16 + seg];
            bypass_store16B(h0_nxt + (size_t)(cluster * 32 + row) * HID + r0 + seg, v);
        }
        cluster_barrier(bar, ++barcount * 64u);
    }

    // ---- epilogue: G2(255) -> h1 final (parity 0) ----
    {
        const unsigned short* h0_cur = h0buf;                 // parity 0 (G1(255))
        const unsigned short* h1_prv = h1buf + (size_t)BH;    // parity 1 (G2(254))
        unsigned short*       h1_new = h1buf;                 // parity 0

        const unsigned short* pa2 = (wave < 4 ? h0_cur : h1_prv) + rowbase + (wave & 3) * 256;
        const unsigned short* pb2 = pa2 + (size_t)16 * HID;

        bf16x8 A0, A1, A2, A3, A4, A5, A6, A7;
        bf16x8 C0, C1, C2, C3, C4, C5, C6, C7;
        asm volatile(
            "global_load_dwordx4 %0, %16, off sc0 sc1\n\t"
            "global_load_dwordx4 %1, %16, off offset:64 sc0 sc1\n\t"
            "global_load_dwordx4 %2, %16, off offset:128 sc0 sc1\n\t"
            "global_load_dwordx4 %3, %16, off offset:192 sc0 sc1\n\t"
            "global_load_dwordx4 %4, %16, off offset:256 sc0 sc1\n\t"
            "global_load_dwordx4 %5, %16, off offset:320 sc0 sc1\n\t"
            "global_load_dwordx4 %6, %16, off offset:384 sc0 sc1\n\t"
            "global_load_dwordx4 %7, %16, off offset:448 sc0 sc1\n\t"
            "global_load_dwordx4 %8, %17, off sc0 sc1\n\t"
            "global_load_dwordx4 %9, %17, off offset:64 sc0 sc1\n\t"
            "global_load_dwordx4 %10, %17, off offset:128 sc0 sc1\n\t"
            "global_load_dwordx4 %11, %17, off offset:192 sc0 sc1\n\t"
            "global_load_dwordx4 %12, %17, off offset:256 sc0 sc1\n\t"
            "global_load_dwordx4 %13, %17, off offset:320 sc0 sc1\n\t"
            "global_load_dwordx4 %14, %17, off offset:384 sc0 sc1\n\t"
            "global_load_dwordx4 %15, %17, off offset:448 sc0 sc1\n\t"
            "s_waitcnt vmcnt(0)"
            : "=&v"(A0), "=&v"(A1), "=&v"(A2), "=&v"(A3),
              "=&v"(A4), "=&v"(A5), "=&v"(A6), "=&v"(A7),
              "=&v"(C0), "=&v"(C1), "=&v"(C2), "=&v"(C3),
              "=&v"(C4), "=&v"(C5), "=&v"(C6), "=&v"(C7)
            : "v"(pa2), "v"(pb2)
            : "memory");

        f32x4 d0 = {0.f,0.f,0.f,0.f}, d1 = {0.f,0.f,0.f,0.f};
        d0 = __builtin_amdgcn_mfma_f32_16x16x32_bf16(A0, bw2[0], d0, 0,0,0);
        d1 = __builtin_amdgcn_mfma_f32_16x16x32_bf16(C0, bw2[0], d1, 0,0,0);
        d0 = __builtin_amdgcn_mfma_f32_16x16x32_bf16(A1, bw2[1], d0, 0,0,0);
        d1 = __builtin_amdgcn_mfma_f32_16x16x32_bf16(C1, bw2[1], d1, 0,0,0);
        d0 = __builtin_amdgcn_mfma_f32_16x16x32_bf16(A2, bw2[2], d0, 0,0,0);
        d1 = __builtin_amdgcn_mfma_f32_16x16x32_bf16(C2, bw2[2], d1, 0,0,0);
        d0 = __builtin_amdgcn_mfma_f32_16x16x32_bf16(A3, bw2[3], d0, 0,0,0);
        d1 = __builtin_amdgcn_mfma_f32_16x16x32_bf16(C3, bw2[3], d1, 0,0,0);
        d0 = __builtin_amdgcn_mfma_f32_16x16x32_bf16(A4, bw2[4], d0, 0,0,0);
        d1 = __builtin_amdgcn_mfma_f32_16x16x32_bf16(C4, bw2[4], d1, 0,0,0);
        d0 = __builtin_amdgcn_mfma_f32_16x16x32_bf16(A5, bw2[5], d0, 0,0,0);
        d1 = __builtin_amdgcn_mfma_f32_16x16x32_bf16(C5, bw2[5], d1, 0,0,0);
        d0 = __builtin_amdgcn_mfma_f32_16x16x32_bf16(A6, bw2[6], d0, 0,0,0);
        d1 = __builtin_amdgcn_mfma_f32_16x16x32_bf16(C6, bw2[6], d1, 0,0,0);
        d0 = __builtin_amdgcn_mfma_f32_16x16x32_bf16(A7, bw2[7], d0, 0,0,0);
        d1 = __builtin_amdgcn_mfma_f32_16x16x32_bf16(C7, bw2[7], d1, 0,0,0);

        #pragma unroll
        for (int r = 0; r < 4; ++r) {
            const int idx = (q * 4 + r) * 16 + nl;
            partials[wave][0][idx] = d0[r];
            partials[wave][1][idx] = d1[r];
        }
        __syncthreads();
        {
            const int idx = row_r * 16 + nn;
            float s1 = bias1_reg;
            #pragma unroll
            for (int w = 0; w < 8; ++w) s1 += partials[w][mt_r][idx];
            hst[1][b_l * 16 + nn] = f2bf(tanhf(s1));
        }
        __syncthreads();
        if (wave == 0) {
            const int row = lane >> 1, seg = (lane & 1) * 8;
            i32x4 v = *(const i32x4*)&hst[1][row * 16 + seg];
            bypass_store16B(h1_new + (size_t)(cluster * 32 + row) * HID + r0 + seg, v);
        }
        cluster_barrier(bar, ++barcount * 64u);
    }

    // ---- FC head: out = h1_final @ fcw^T + fcb; wg0 of each cluster ----
    if (wg == 0) {
        const int o = tid & 3, b = (tid >> 2) & 31, seg = tid >> 7;   // 4-way K split
        const unsigned short* hp = h1buf + (size_t)(cluster * 32 + b) * HID + seg * 256;
        const float* wp = fcw + (size_t)o * HID + seg * 256;
        float s = 0.f;
        #pragma unroll 1
        for (int blk = 0; blk < 4; ++blk) {
            bf16x8 h8[8];
            bypass_ld8_seq(hp + blk * 64, h8);
            #pragma unroll
            for (int i = 0; i < 8; ++i) {
                const float* w = wp + blk * 64 + i * 8;
                #pragma unroll
                for (int e = 0; e < 8; ++e)
                    s += bf2f((unsigned short)h8[i][e]) * w[e];
            }
        }
        float* red = (float*)partials;
        red[tid] = s;
        __syncthreads();
        if (seg == 0)
            out[(cluster * 32 + b) * OUTN + o] =
                fcb[o] + red[tid] + red[tid + 128] + red[tid + 256] + red[tid + 384];
    }
}

// ---------------------------------------------------------------------------
extern "C" void kernel_launch(void* const* d_in, const int* in_sizes, int n_in,
                              void* d_out, int out_size, void* d_ws, size_t ws_size,
                              hipStream_t stream) {
    const int*   fx   = (const int*)d_in[0];
    const float* emb  = (const float*)d_in[1];
    const float* wx0  = (const float*)d_in[2];
    const float* bx0  = (const float*)d_in[3];
    const float* whh0 = (const float*)d_in[4];
    const float* bh0  = (const float*)d_in[5];
    const float* wx1  = (const float*)d_in[6];
    const float* bx1  = (const float*)d_in[7];
    const float* whh1 = (const float*)d_in[8];
    const float* bh1  = (const float*)d_in[9];
    const float* fcw  = (const float*)d_in[10];
    const float* fcb  = (const float*)d_in[11];
    float* outp = (float*)d_out;

    char* ws = (char*)d_ws;
    unsigned*       bars  = (unsigned*)ws;                              // 4 KB
    unsigned short* h0buf = (unsigned short*)(ws + 4096);               // 512 KB
    unsigned short* h1buf = (unsigned short*)(ws + 4096 + 524288);      // 512 KB
    unsigned short* pre0  = (unsigned short*)(ws + 4096 + 2 * 524288);  // 64 MB bf16

    // zero barriers + h state (ws is poisoned 0xAA before every call)
    hipMemsetAsync(d_ws, 0, 4096 + 2 * 524288, stream);

    prefx_kernel<<<dim3(2048), dim3(256), 0, stream>>>(fx, emb, wx0, bx0, bh0, pre0);

    void* kargs[] = {(void*)&pre0, (void*)&whh0, (void*)&wx1, (void*)&whh1,
                     (void*)&bx1, (void*)&bh1, (void*)&fcw, (void*)&fcb,
                     (void*)&h0buf, (void*)&h1buf, (void*)&bars, (void*)&outp};
    hipLaunchCooperativeKernel((void*)rnn_step_kernel, dim3(256), dim3(512),
                               kargs, 0, stream);
}

// Round 6
// 1593.162 us; speedup vs baseline: 2.5813x; 1.4948x over previous
//
#include <hip/hip_runtime.h>
#include <hip/hip_bf16.h>

#define HID   1024
#define EMB   512
#define BATCH 128
#define TT    256
#define OUTN  4
#define BH    (BATCH * HID)

typedef short bf16x8 __attribute__((ext_vector_type(8)));   // 8 bf16 in 4 VGPRs
typedef float f32x4  __attribute__((ext_vector_type(4)));
typedef int   i32x4  __attribute__((ext_vector_type(4)));

__device__ __forceinline__ float bf2f(unsigned short h) {
    return __uint_as_float(((unsigned)h) << 16);
}
__device__ __forceinline__ unsigned short f2bf(float f) {
    unsigned u = __float_as_uint(f);
    u += 0x7FFFu + ((u >> 16) & 1u);      // RNE
    return (unsigned short)(u >> 16);
}
__device__ __forceinline__ void cvt8(const float* s, unsigned short* d) {
    float4 a = *(const float4*)s, b = *(const float4*)(s + 4);
    unsigned short t[8] = {f2bf(a.x), f2bf(a.y), f2bf(a.z), f2bf(a.w),
                           f2bf(b.x), f2bf(b.y), f2bf(b.z), f2bf(b.w)};
    *(int4*)d = *(const int4*)t;
}
__device__ __forceinline__ bf16x8 pack8(const float* s) {
    float4 a = *(const float4*)s, b = *(const float4*)(s + 4);
    bf16x8 f;
    f[0] = (short)f2bf(a.x); f[1] = (short)f2bf(a.y);
    f[2] = (short)f2bf(a.z); f[3] = (short)f2bf(a.w);
    f[4] = (short)f2bf(b.x); f[5] = (short)f2bf(b.y);
    f[6] = (short)f2bf(b.z); f[7] = (short)f2bf(b.w);
    return f;
}

// ---------------------------------------------------------------------------
// Phase A: pre0[t*128+b][i] = emb[fx[b][t]] . Wx0[i] + bx0[i] + bh0[i] (bf16 out)
// Unchanged from the round-3 run that passed.
// ---------------------------------------------------------------------------
__global__ __launch_bounds__(256) void prefx_kernel(
    const int* __restrict__ fx, const float* __restrict__ emb,
    const float* __restrict__ wx0, const float* __restrict__ bx0,
    const float* __restrict__ bh0, unsigned short* __restrict__ pre0)
{
    __shared__ __align__(16) unsigned short A[64 * 520];
    const int mtile = blockIdx.x >> 2;
    const int ntile = blockIdx.x & 3;
    const int tid = threadIdx.x;

    {
        const int row = tid >> 2, part = tid & 3;
        const int r = mtile * 64 + row;
        const int t = r >> 7, b = r & 127;
        const int v = fx[b * TT + t];
        const float* src = emb + (size_t)v * EMB + part * 128;
        unsigned short* dst = A + row * 520 + part * 128;
        #pragma unroll
        for (int i = 0; i < 128; i += 8) cvt8(src + i, dst + i);
    }
    __syncthreads();

    const int wave = tid >> 6, lane = tid & 63, q = lane >> 4, nl = lane & 15;
    const int col0 = ntile * 256 + wave * 64;

    f32x4 acc[4][4] = {};
    for (int kc = 0; kc < 16; ++kc) {
        bf16x8 bfr[4], afr[4];
        #pragma unroll
        for (int nt = 0; nt < 4; ++nt)
            bfr[nt] = pack8(wx0 + (size_t)(col0 + nt * 16 + nl) * EMB + kc * 32 + q * 8);
        #pragma unroll
        for (int mt = 0; mt < 4; ++mt)
            afr[mt] = *(const bf16x8*)(A + (mt * 16 + nl) * 520 + kc * 32 + q * 8);
        #pragma unroll
        for (int mt = 0; mt < 4; ++mt)
            #pragma unroll
            for (int nt = 0; nt < 4; ++nt)
                acc[mt][nt] = __builtin_amdgcn_mfma_f32_16x16x32_bf16(afr[mt], bfr[nt], acc[mt][nt], 0, 0, 0);
    }

    #pragma unroll
    for (int nt = 0; nt < 4; ++nt) {
        const int gc = col0 + nt * 16 + nl;
        const float bias = bx0[gc] + bh0[gc];
        #pragma unroll
        for (int mt = 0; mt < 4; ++mt)
            #pragma unroll
            for (int r = 0; r < 4; ++r) {
                const int grow = mtile * 64 + mt * 16 + q * 4 + r;
                pre0[(size_t)grow * HID + gc] = f2bf(acc[mt][nt][r] + bias);
            }
    }
}

// ---------------------------------------------------------------------------
// MALL-coherent bypass helpers (sc0 sc1) — proven in round 3. Every vmem asm
// block ends with s_waitcnt vmcnt(0).
// ---------------------------------------------------------------------------
__device__ __forceinline__ void bypass_store16B(unsigned short* dst, i32x4 v) {
    asm volatile("global_store_dwordx4 %0, %1, off sc0 sc1\n\t"
                 "s_waitcnt vmcnt(0)"
                 :: "v"(dst), "v"(v) : "memory");
}

// 8 x 16B from p2 (strided 64B) + 4 x 16B from p1 (strided 64B)
__device__ __forceinline__ void bypass_load12(const unsigned short* p2,
                                              const unsigned short* p1,
                                              bf16x8 A[8], bf16x8 E[4]) {
    asm volatile(
        "global_load_dwordx4 %0, %12, off sc0 sc1\n\t"
        "global_load_dwordx4 %1, %12, off offset:64 sc0 sc1\n\t"
        "global_load_dwordx4 %2, %12, off offset:128 sc0 sc1\n\t"
        "global_load_dwordx4 %3, %12, off offset:192 sc0 sc1\n\t"
        "global_load_dwordx4 %4, %12, off offset:256 sc0 sc1\n\t"
        "global_load_dwordx4 %5, %12, off offset:320 sc0 sc1\n\t"
        "global_load_dwordx4 %6, %12, off offset:384 sc0 sc1\n\t"
        "global_load_dwordx4 %7, %12, off offset:448 sc0 sc1\n\t"
        "global_load_dwordx4 %8, %13, off sc0 sc1\n\t"
        "global_load_dwordx4 %9, %13, off offset:64 sc0 sc1\n\t"
        "global_load_dwordx4 %10, %13, off offset:128 sc0 sc1\n\t"
        "global_load_dwordx4 %11, %13, off offset:192 sc0 sc1\n\t"
        "s_waitcnt vmcnt(0)"
        : "=&v"(A[0]), "=&v"(A[1]), "=&v"(A[2]), "=&v"(A[3]),
          "=&v"(A[4]), "=&v"(A[5]), "=&v"(A[6]), "=&v"(A[7]),
          "=&v"(E[0]), "=&v"(E[1]), "=&v"(E[2]), "=&v"(E[3])
        : "v"(p2), "v"(p1) : "memory");
}

__device__ __forceinline__ void bypass_ld8_seq(const unsigned short* p, bf16x8 r[8]) {
    asm volatile(
        "global_load_dwordx4 %0, %8, off sc0 sc1\n\t"
        "global_load_dwordx4 %1, %8, off offset:16 sc0 sc1\n\t"
        "global_load_dwordx4 %2, %8, off offset:32 sc0 sc1\n\t"
        "global_load_dwordx4 %3, %8, off offset:48 sc0 sc1\n\t"
        "global_load_dwordx4 %4, %8, off offset:64 sc0 sc1\n\t"
        "global_load_dwordx4 %5, %8, off offset:80 sc0 sc1\n\t"
        "global_load_dwordx4 %6, %8, off offset:96 sc0 sc1\n\t"
        "global_load_dwordx4 %7, %8, off offset:112 sc0 sc1\n\t"
        "s_waitcnt vmcnt(0)"
        : "=&v"(r[0]), "=&v"(r[1]), "=&v"(r[2]), "=&v"(r[3]),
          "=&v"(r[4]), "=&v"(r[5]), "=&v"(r[6]), "=&v"(r[7])
        : "v"(p) : "memory");
}

// Cluster barrier: relaxed agent-scope atomics only (proven in round 3).
__device__ __forceinline__ void cluster_barrier(unsigned* bar, unsigned target) {
    __syncthreads();
    if (threadIdx.x == 0) {
        __hip_atomic_fetch_add(bar, 1u, __ATOMIC_RELAXED, __HIP_MEMORY_SCOPE_AGENT);
        while (__hip_atomic_load(bar, __ATOMIC_RELAXED, __HIP_MEMORY_SCOPE_AGENT) < target)
            __builtin_amdgcn_s_sleep(2);
    }
    __syncthreads();
}

// ---------------------------------------------------------------------------
// Phase B: persistent recurrence. 256 WGs x 512 thr, 1 WG/CU (90 KB LDS).
// 8 clusters x 32 WGs; cluster c owns batch rows [16c,16c+16); WG owns 32 cols.
// Superstep t: load [G2(t) + G1(t+1)] -> MFMA -> LDS reduce -> store
// h1(t), h0(t+1) -> one barrier. Weights live in registers (24 bf16x8 frags).
// ---------------------------------------------------------------------------
__global__ __launch_bounds__(512) void rnn_step_kernel(
    const unsigned short* __restrict__ pre0,
    const float* __restrict__ whh0,
    const float* __restrict__ wx1,
    const float* __restrict__ whh1,
    const float* __restrict__ bx1,
    const float* __restrict__ bh1,
    const float* __restrict__ fcw,
    const float* __restrict__ fcb,
    unsigned short* __restrict__ h0buf,     // [2][128][1024] bf16 (zeroed)
    unsigned short* __restrict__ h1buf,     // [2][128][1024] bf16 (zeroed)
    unsigned* __restrict__ bars,            // 4 KB barrier region (zeroed)
    float* __restrict__ out)                // [128][4] f32
{
    __shared__ __align__(16) float ldsbuf[22528];   // 90112 B -> 1 WG/CU
    float* partials = ldsbuf;                                   // [8][4][272]
    unsigned short* hst0 = (unsigned short*)(ldsbuf + 8704);    // [16][32]
    unsigned short* hst1 = (unsigned short*)(ldsbuf + 8704) + 512;
    #define PT(w, t, i) partials[((w) * 4 + (t)) * 272 + (i)]

    const int bid = blockIdx.x;
    const int cluster = bid & 7;
    const int wg = bid >> 3;                 // 0..31
    const int r0 = wg * 32;
    const int tid = threadIdx.x;
    const int wave = tid >> 6, lane = tid & 63, q = lane >> 4, nl = lane & 15;

    // ---- step-invariant weight fragments in registers (24 frags, 96 VGPR) ----
    // B-frag for n-tile ct: W row (r0+ct*16+nl), k = chunk*32 + q*8.
    bf16x8 bw1[2][4], bw2[2][8];
    {
        const int koff1 = wave * 128;                 // G1 chunks wave*4+j
        #pragma unroll
        for (int ct = 0; ct < 2; ++ct)
            #pragma unroll
            for (int j = 0; j < 4; ++j)
                bw1[ct][j] = pack8(whh0 + (size_t)(r0 + ct * 16 + nl) * HID + koff1 + j * 32 + q * 8);
        const float* src2 = (wave < 4) ? wx1 : whh1;  // G2 chunks wave*8+j
        const int koff2 = (wave & 3) * 256;
        #pragma unroll
        for (int ct = 0; ct < 2; ++ct)
            #pragma unroll
            for (int j = 0; j < 8; ++j)
                bw2[ct][j] = pack8(src2 + (size_t)(r0 + ct * 16 + nl) * HID + koff2 + j * 32 + q * 8);
    }

    const int row_r = tid >> 5;              // 0..15: batch row (reduce phase)
    const int col_l = tid & 31;              // 0..31: local HID col
    const int ct_r = (tid >> 4) & 1;         // which 16-col tile
    const float bias1 = bx1[r0 + col_l] + bh1[r0 + col_l];

    const size_t arow = (size_t)(cluster * 16 + nl) * HID + q * 8;
    unsigned barcount = 0;
    unsigned* bar = bars + cluster * 64;     // 256B-separated counters

    // ---- prologue: h0(0) = tanh(pre0(0)) (h0 init = 0), store parity 1 ----
    {
        const float pv = bf2f(pre0[(size_t)(cluster * 16 + row_r) * HID + r0 + col_l]);
        hst0[row_r * 32 + col_l] = f2bf(tanhf(pv));
        __syncthreads();
        if (wave == 1) {
            const int row = lane >> 2, seg = (lane & 3) * 8;
            i32x4 v = *(const i32x4*)&hst0[row * 32 + seg];
            bypass_store16B(h0buf + (size_t)BH + (size_t)(cluster * 16 + row) * HID + r0 + seg, v);
        }
        cluster_barrier(bar, ++barcount * 32u);
    }

    // ---- main loop: superstep t = [G2(t) || G1(t+1)] ----
    #pragma unroll 1
    for (int t = 0; t < TT - 1; ++t) {
        const int pin = t & 1;
        const unsigned short* h0_cur = h0buf + (size_t)(pin ^ 1) * BH;  // G1(t) out
        unsigned short*       h0_nxt = h0buf + (size_t)pin * BH;        // G1(t+1) dest
        const unsigned short* h1_prv = h1buf + (size_t)pin * BH;        // G2(t-1) out
        unsigned short*       h1_new = h1buf + (size_t)(pin ^ 1) * BH;  // G2(t) dest

        const float pre_v = bf2f(pre0[(size_t)((t + 1) * BATCH + cluster * 16 + row_r) * HID + r0 + col_l]);

        const unsigned short* p2 = (wave < 4 ? h0_cur : h1_prv) + arow + (wave & 3) * 256;
        const unsigned short* p1 = h0_cur + arow + wave * 128;

        bf16x8 A[8], E[4];
        bypass_load12(p2, p1, A, E);

        f32x4 d0 = {0.f,0.f,0.f,0.f}, d1 = {0.f,0.f,0.f,0.f};   // G2, tiles 0/1
        f32x4 c0 = {0.f,0.f,0.f,0.f}, c1 = {0.f,0.f,0.f,0.f};   // G1-next
        #pragma unroll
        for (int j = 0; j < 8; ++j) {
            d0 = __builtin_amdgcn_mfma_f32_16x16x32_bf16(A[j], bw2[0][j], d0, 0,0,0);
            d1 = __builtin_amdgcn_mfma_f32_16x16x32_bf16(A[j], bw2[1][j], d1, 0,0,0);
        }
        #pragma unroll
        for (int j = 0; j < 4; ++j) {
            c0 = __builtin_amdgcn_mfma_f32_16x16x32_bf16(E[j], bw1[0][j], c0, 0,0,0);
            c1 = __builtin_amdgcn_mfma_f32_16x16x32_bf16(E[j], bw1[1][j], c1, 0,0,0);
        }

        #pragma unroll
        for (int r = 0; r < 4; ++r) {
            const int idx = (q * 4 + r) * 17 + nl;
            PT(wave, 0, idx) = d0[r];
            PT(wave, 1, idx) = d1[r];
            PT(wave, 2, idx) = c0[r];
            PT(wave, 3, idx) = c1[r];
        }
        __syncthreads();
        {
            const int idx = row_r * 17 + (col_l & 15);
            float s1 = bias1, s0 = pre_v;
            #pragma unroll
            for (int w = 0; w < 8; ++w) {
                s1 += PT(w, ct_r, idx);
                s0 += PT(w, 2 + ct_r, idx);
            }
            hst1[row_r * 32 + col_l] = f2bf(tanhf(s1));   // h1(t)
            hst0[row_r * 32 + col_l] = f2bf(tanhf(s0));   // h0(t+1)
        }
        __syncthreads();

        if (wave == 0) {
            const int row = lane >> 2, seg = (lane & 3) * 8;
            i32x4 v = *(const i32x4*)&hst1[row * 32 + seg];
            bypass_store16B(h1_new + (size_t)(cluster * 16 + row) * HID + r0 + seg, v);
        } else if (wave == 1) {
            const int row = lane >> 2, seg = (lane & 3) * 8;
            i32x4 v = *(const i32x4*)&hst0[row * 32 + seg];
            bypass_store16B(h0_nxt + (size_t)(cluster * 16 + row) * HID + r0 + seg, v);
        }
        cluster_barrier(bar, ++barcount * 32u);
    }

    // ---- epilogue: G2(255) -> h1 final (parity 0) ----
    {
        const unsigned short* h0_cur = h0buf;                 // parity 0
        const unsigned short* h1_prv = h1buf + (size_t)BH;    // parity 1
        unsigned short*       h1_new = h1buf;                 // parity 0

        const unsigned short* p2 = (wave < 4 ? h0_cur : h1_prv) + arow + (wave & 3) * 256;
        const unsigned short* p1 = h0_cur + arow + wave * 128;   // dummy (valid mem)

        bf16x8 A[8], E[4];
        bypass_load12(p2, p1, A, E);

        f32x4 d0 = {0.f,0.f,0.f,0.f}, d1 = {0.f,0.f,0.f,0.f};
        #pragma unroll
        for (int j = 0; j < 8; ++j) {
            d0 = __builtin_amdgcn_mfma_f32_16x16x32_bf16(A[j], bw2[0][j], d0, 0,0,0);
            d1 = __builtin_amdgcn_mfma_f32_16x16x32_bf16(A[j], bw2[1][j], d1, 0,0,0);
        }
        #pragma unroll
        for (int r = 0; r < 4; ++r) {
            const int idx = (q * 4 + r) * 17 + nl;
            PT(wave, 0, idx) = d0[r];
            PT(wave, 1, idx) = d1[r];
        }
        __syncthreads();
        {
            const int idx = row_r * 17 + (col_l & 15);
            float s1 = bias1;
            #pragma unroll
            for (int w = 0; w < 8; ++w) s1 += PT(w, ct_r, idx);
            hst1[row_r * 32 + col_l] = f2bf(tanhf(s1));
        }
        __syncthreads();
        if (wave == 0) {
            const int row = lane >> 2, seg = (lane & 3) * 8;
            i32x4 v = *(const i32x4*)&hst1[row * 32 + seg];
            bypass_store16B(h1_new + (size_t)(cluster * 16 + row) * HID + r0 + seg, v);
        }
        cluster_barrier(bar, ++barcount * 32u);
    }

    // ---- FC head: out = h1_final @ fcw^T + fcb; wg0 of each cluster ----
    if (wg == 0) {
        const int o = tid & 3, row = (tid >> 2) & 15, seg = tid >> 6;  // 8-way K split
        const unsigned short* hp = h1buf + (size_t)(cluster * 16 + row) * HID + seg * 128;
        const float* wp = fcw + (size_t)o * HID + seg * 128;
        float s = 0.f;
        bf16x8 h8[8];
        #pragma unroll 1
        for (int half = 0; half < 2; ++half) {
            bypass_ld8_seq(hp + half * 64, h8);
            #pragma unroll
            for (int i = 0; i < 8; ++i) {
                const float* w = wp + half * 64 + i * 8;
                #pragma unroll
                for (int e = 0; e < 8; ++e)
                    s += bf2f((unsigned short)h8[i][e]) * w[e];
            }
        }
        float* red = ldsbuf;
        red[tid] = s;
        __syncthreads();
        if (tid < 64) {
            float acc = fcb[o];
            #pragma unroll
            for (int sg = 0; sg < 8; ++sg) acc += red[tid + sg * 64];
            out[(cluster * 16 + row) * OUTN + o] = acc;
        }
    }
    #undef PT
}

// ---------------------------------------------------------------------------
extern "C" void kernel_launch(void* const* d_in, const int* in_sizes, int n_in,
                              void* d_out, int out_size, void* d_ws, size_t ws_size,
                              hipStream_t stream) {
    const int*   fx   = (const int*)d_in[0];
    const float* emb  = (const float*)d_in[1];
    const float* wx0  = (const float*)d_in[2];
    const float* bx0  = (const float*)d_in[3];
    const float* whh0 = (const float*)d_in[4];
    const float* bh0  = (const float*)d_in[5];
    const float* wx1  = (const float*)d_in[6];
    const float* bx1  = (const float*)d_in[7];
    const float* whh1 = (const float*)d_in[8];
    const float* bh1  = (const float*)d_in[9];
    const float* fcw  = (const float*)d_in[10];
    const float* fcb  = (const float*)d_in[11];
    float* outp = (float*)d_out;

    // Workspace layout — EXACTLY the round-3-proven 68,161,536-byte footprint.
    char* ws = (char*)d_ws;
    unsigned*       bars  = (unsigned*)ws;                              // 4 KB
    unsigned short* h0buf = (unsigned short*)(ws + 4096);               // 512 KB
    unsigned short* h1buf = (unsigned short*)(ws + 4096 + 524288);      // 512 KB
    unsigned short* pre0  = (unsigned short*)(ws + 4096 + 2 * 524288);  // 64 MB bf16

    // zero barriers + h state (ws is poisoned 0xAA before every call)
    hipMemsetAsync(d_ws, 0, 4096 + 2 * 524288, stream);

    prefx_kernel<<<dim3(2048), dim3(256), 0, stream>>>(fx, emb, wx0, bx0, bh0, pre0);

    void* kargs[] = {(void*)&pre0, (void*)&whh0, (void*)&wx1, (void*)&whh1,
                     (void*)&bx1, (void*)&bh1, (void*)&fcw, (void*)&fcb,
                     (void*)&h0buf, (void*)&h1buf, (void*)&bars, (void*)&outp};
    hipLaunchCooperativeKernel((void*)rnn_step_kernel, dim3(256), dim3(512),
                               kargs, 0, stream);
}